// Round 7
// baseline (156.505 us; speedup 1.0000x reference)
//
#include <hip/hip_runtime.h>
#include <math.h>

#define N_PATHS 23
#define HIDDEN  32
#define N_NODES 4096
#define N_EDGES 8192
#define FEAT    512
#define EB      8     // edges per block (4 per wave)
#define BLK     128   // 2 waves

// wave-local LDS phase separator: all prior DS ops complete; compiler may not reorder
#define WAVE_SYNC() asm volatile("s_waitcnt lgkmcnt(0)" ::: "memory")

typedef __attribute__((ext_vector_type(8))) short bf16x8;
typedef __attribute__((ext_vector_type(4))) float f32x4;

// ---- path metadata (PATHS enumeration order: l1 outer, l2, l3) ----
__device__ const int P_L1[N_PATHS] = {0,0,0,0, 1,1,1,1,1,1, 2,2,2,2,2,2,2, 3,3,3,3,3,3};
__device__ const int P_L2[N_PATHS] = {0,1,2,3, 0,1,1,2,2,3, 0,1,1,2,2,3,3, 0,1,2,2,3,3};
__device__ const int P_L3[N_PATHS] = {0,1,2,3, 1,0,2,1,3,2, 2,1,3,0,2,1,3, 3,2,1,3,0,2};
__device__ const int C_OFF[N_PATHS] = {0,1,10,35,84,93,102,147,192,297,402,427,472,577,602,727,832,1077,1126,1231,1336,1581,1630};
__device__ const int CNT_L3[4] = {4,6,7,6};
// paths grouped by l3
__device__ const int L3PATHS[N_PATHS] = {0,5,13,21, 1,4,7,11,15,19, 2,6,9,10,14,18,22, 3,8,12,16,17,20};
__device__ const int L3START[5] = {0,4,10,17,23};
__device__ const int OFF3[4] = {0,32,128,288};

// ---- 16-point Gauss-Legendre nodes/weights ----
__device__ const double GLX[16] = {
    -0.98940093499164993, -0.94457502307323258, -0.86563120238783174, -0.75540440835500303,
    -0.61787624440264375, -0.45801677765722739, -0.28160355077925891, -0.09501250983763744,
     0.09501250983763744,  0.28160355077925891,  0.45801677765722739,  0.61787624440264375,
     0.75540440835500303,  0.86563120238783174,  0.94457502307323258,  0.98940093499164993};
__device__ const double GLW[16] = {
     0.02715245941175409,  0.06225352393864789,  0.09515851168249278,  0.12462897125553387,
     0.14959598881657673,  0.16915651939500254,  0.18260341504492359,  0.18945061045506850,
     0.18945061045506850,  0.18260341504492359,  0.16915651939500254,  0.14959598881657673,
     0.12462897125553387,  0.09515851168249278,  0.06225352393864789,  0.02715245941175409};

// cos/sin(k*pi/16), exact literals
__device__ const double COSP[32] = {
  1.0,                    0.980785280403230449,  0.923879532511286756,  0.831469612302545237,
  0.707106781186547524,   0.555570233019602225,  0.382683432365089772,  0.195090322016128268,
  0.0,                   -0.195090322016128268, -0.382683432365089772, -0.555570233019602225,
 -0.707106781186547524,  -0.831469612302545237, -0.923879532511286756, -0.980785280403230449,
 -1.0,                   -0.980785280403230449, -0.923879532511286756, -0.831469612302545237,
 -0.707106781186547524,  -0.555570233019602225, -0.382683432365089772, -0.195090322016128268,
  0.0,                    0.195090322016128268,  0.382683432365089772,  0.555570233019602225,
  0.707106781186547524,   0.831469612302545237,  0.923879532511286756,  0.980785280403230449};
__device__ const double SINP[32] = {
  0.0,                    0.195090322016128268,  0.382683432365089772,  0.555570233019602225,
  0.707106781186547524,   0.831469612302545237,  0.923879532511286756,  0.980785280403230449,
  1.0,                    0.980785280403230449,  0.923879532511286756,  0.831469612302545237,
  0.707106781186547524,   0.555570233019602225,  0.382683432365089772,  0.195090322016128268,
  0.0,                   -0.195090322016128268, -0.382683432365089772, -0.555570233019602225,
 -0.707106781186547524,  -0.831469612302545237, -0.923879532511286756, -0.980785280403230449,
 -1.0,                   -0.980785280403230449, -0.923879532511286756, -0.831469612302545237,
 -0.707106781186547524,  -0.555570233019602225, -0.382683432365089772, -0.195090322016128268};

__device__ inline void sh_f64(double x, double y, double z, double* Y) {
    const double s3 = 1.7320508075688772935, s5 = 2.2360679774997896964,
                 s7 = 2.6457513110645905905, s15 = 3.8729833462074168852;
    const double c58 = 0.79056941504209483300, c38 = 0.61237243569579452455;
    Y[0] = 1.0;
    Y[1] = s3*x;  Y[2] = s3*y;  Y[3] = s3*z;
    Y[4] = s5*s3*x*z;  Y[5] = s5*s3*x*y;
    Y[6] = s5*(y*y - 0.5*(x*x + z*z));
    Y[7] = s5*s3*y*z;  Y[8] = s5*(s3/2.0)*(z*z - x*x);
    Y[9] = s7*c58*x*(3.0*z*z - x*x);
    Y[10]= s7*s15*x*y*z;
    Y[11]= s7*c38*x*(5.0*y*y - 1.0);
    Y[12]= s7*0.5*y*(5.0*y*y - 3.0);
    Y[13]= s7*c38*z*(5.0*y*y - 1.0);
    Y[14]= s7*(s15/2.0)*y*(z*z - x*x);
    Y[15]= s7*c58*z*(z*z - 3.0*x*x);
}

__device__ inline void sh_f32(float x, float y, float z, float* Y) {
    const float s3 = 1.73205080757f, s5 = 2.23606797750f, s7 = 2.64575131106f, s15 = 3.87298334621f;
    const float c58 = 0.79056941504f, c38 = 0.61237243570f;
    Y[0] = 1.0f;
    Y[1] = s3*x;  Y[2] = s3*y;  Y[3] = s3*z;
    Y[4] = s15*x*z;  Y[5] = s15*x*y;
    Y[6] = s5*(y*y - 0.5f*(x*x + z*z));
    Y[7] = s15*y*z;  Y[8] = s5*(s3*0.5f)*(z*z - x*x);
    Y[9] = s7*c58*x*(3.0f*z*z - x*x);
    Y[10]= s7*s15*x*y*z;
    Y[11]= s7*c38*x*(5.0f*y*y - 1.0f);
    Y[12]= s7*0.5f*y*(5.0f*y*y - 3.0f);
    Y[13]= s7*c38*z*(5.0f*y*y - 1.0f);
    Y[14]= s7*(s15*0.5f)*y*(z*z - x*x);
    Y[15]= s7*c58*z*(z*z - 3.0f*x*x);
}

__device__ inline unsigned short bf16rne(float x) {
    unsigned int u = __float_as_uint(x);
    unsigned int r = (u + 0x7FFFu + ((u >> 16) & 1u)) >> 16;
    return (unsigned short)r;
}
__device__ inline float bf16f(unsigned short h) {
    return __uint_as_float(((unsigned int)h) << 16);
}

// ---- setup: W3J tables + weight transpose (wprep folded in) ----
__global__ __launch_bounds__(512) void w3j_setup_kernel(
    const float* __restrict__ ww, const float* __restrict__ wb,
    float* __restrict__ g_w3j,
    unsigned short* __restrict__ Awhi, unsigned short* __restrict__ Awlo,
    unsigned short* __restrict__ Abhi, unsigned short* __restrict__ Ablo) {
    __shared__ float s_Yq[512][17];   // pad 17: bank spread for q-stride-4 reads
    __shared__ float s_wq[512];
    __shared__ float s_part[256];
    __shared__ float red[256];
    __shared__ float s_scale;

    const int p = blockIdx.x;
    const int t = threadIdx.x;
    const int l1 = P_L1[p], l2 = P_L2[p], l3 = P_L3[p];
    const int d2 = 2*l2+1, d3 = 2*l3+1;
    const int csize = (2*l1+1)*d2*d3;
    const double step = 2.0*3.14159265358979323846/32.0;

    // weight transpose tail work (independent of quadrature)
#pragma unroll
    for (int r = 0; r < 2; ++r) {
        const int idx = t + 512*r;
        const int w = idx >> 5, u = idx & 31;
        const float vw = ww[p*1024 + u*32 + w];
        const float vb = wb[p*1024 + u*32 + w];
        const unsigned short hw = bf16rne(vw);
        const unsigned short hb = bf16rne(vb);
        const int o = p*1024 + w*32 + u;
        Awhi[o] = hw;  Awlo[o] = bf16rne(vw - bf16f(hw));
        Abhi[o] = hb;  Ablo[o] = bf16rne(vb - bf16f(hb));
    }

    // phase A: one quadrature point per thread
    {
        const int q = t, iu = q >> 5, ip = q & 31;
        const double u = GLX[iu];
        const double st = sqrt(fmax(1.0 - u*u, 0.0));
        double Y[16];
        sh_f64(st*COSP[ip], st*SINP[ip], u, Y);
#pragma unroll
        for (int i = 0; i < 16; ++i) s_Yq[q][i] = (float)Y[i];
        s_wq[q] = (float)(GLW[iu] * step);
    }
    __syncthreads();

    // phase B: 4 threads per entry, 128 interleaved points each, shuffle-reduce
    const int entry0 = t >> 2, sub = t & 3;
#pragma unroll
    for (int pass = 0; pass < 2; ++pass) {
        const int entry = entry0 + pass*128;
        float acc = 0.f;
        if (entry < csize) {
            const int i = entry/(d2*d3); const int r = entry - i*(d2*d3);
            const int j = r/d3; const int k = r - j*d3;
            const int ai = l1*l1+i, bi = l2*l2+j, ci = l3*l3+k;
#pragma unroll 4
            for (int it = 0; it < 128; ++it) {
                const int q = it*4 + sub;
                acc = fmaf(s_wq[q] * s_Yq[q][ai] * s_Yq[q][bi], s_Yq[q][ci], acc);
            }
        }
        acc += __shfl_xor(acc, 1);
        acc += __shfl_xor(acc, 2);
        if (sub == 0 && entry < csize) s_part[entry] = acc;
    }
    __syncthreads();

    if (t < 256) { const float v = (t < csize) ? s_part[t] : 0.f; red[t] = v*v; }
    __syncthreads();
    for (int s = 128; s > 0; s >>= 1) {
        if (t < s) red[t] += red[t+s];
        __syncthreads();
    }
    if (t == 0) {
        const float pw = sqrtf((float)(2*l3+1) / ((float)CNT_L3[l3] * (float)HIDDEN));
        s_scale = pw / sqrtf(red[0]);
    }
    __syncthreads();
    if (t < csize) g_w3j[C_OFF[p] + t] = s_part[t] * s_scale;
}

// ---- tmp compute + B-operand staging (wave-local: 4 edges x 16 u-threads) ----
template<int D1>
__device__ inline void tmp_stage(int lane, int d3,
                                 const float* __restrict__ xrow, // nf + src[el]*FEAT
                                 const float* __restrict__ zw,   // wave's s_zp region
                                 unsigned short* __restrict__ bh,
                                 unsigned short* __restrict__ bl,
                                 int xoff) {
    const int el = lane >> 4, u0 = lane & 15;
    const float* xg = xrow + xoff + 2*u0*D1;
    float xv[2*D1];
#pragma unroll
    for (int i = 0; i < 2*D1; ++i) xv[i] = xg[i];
    const float* zr = zw + el*49;
    for (int k = 0; k < d3; ++k) {
        float t0 = 0.f, t1 = 0.f;
#pragma unroll
        for (int i = 0; i < D1; ++i) {
            const float zz = zr[i*d3 + k];
            t0 = fmaf(xv[i],    zz, t0);
            t1 = fmaf(xv[D1+i], zz, t1);
        }
        const int c = el*d3 + k;
        const unsigned short h0 = bf16rne(t0);
        const unsigned short h1 = bf16rne(t1);
        const unsigned short g0 = bf16rne(t0 - bf16f(h0));
        const unsigned short g1 = bf16rne(t1 - bf16f(h1));
        *(unsigned int*)(bh + c*40 + 2*u0) = (unsigned int)h0 | ((unsigned int)h1 << 16);
        *(unsigned int*)(bl + c*40 + 2*u0) = (unsigned int)g0 | ((unsigned int)g1 << 16);
    }
}

// ---- main: 2 waves/block, fully wave-synchronous (zero __syncthreads) ----
__global__ __launch_bounds__(BLK) void edge_kernel(
    const float* __restrict__ nf,   // (N_NODES, FEAT)
    const int*   __restrict__ eidx, // (2, N_EDGES)
    const float* __restrict__ ev,   // (N_EDGES, 3)
    const float* __restrict__ w3j,  // (1875,)
    const unsigned short* __restrict__ Awhi,
    const unsigned short* __restrict__ Awlo,
    const unsigned short* __restrict__ Abhi,
    const unsigned short* __restrict__ Ablo,
    float*       __restrict__ out)  // (N_NODES, FEAT) pre-zeroed
{
    __shared__ float s_zp[2][4*49];
    __shared__ float s_Y[2][64];
    __shared__ float s_len[2][4];
    __shared__ int   s_src[2][4];
    __shared__ int   s_dst[2][4];
    __shared__ __align__(16) unsigned short s_Bhi[2][1280];  // [col(32)][u(32)+pad8]
    __shared__ __align__(16) unsigned short s_Blo[2][1280];
    __shared__ float s_msg[2][4*FEAT];   // 8 KB per wave

    const int t    = threadIdx.x;
    const int wave = t >> 6;
    const int lane = t & 63;
    const int ln   = lane & 15;    // n / m-low
    const int lq   = lane >> 4;    // quad
    const int e0   = blockIdx.x * EB + wave*4;

    // per-wave prologue: lanes 0-3 handle this wave's 4 edges
    if (lane < 4) {
        const int e = e0 + lane;
        s_src[wave][lane] = eidx[e];
        s_dst[wave][lane] = eidx[N_EDGES + e];
        const float x = ev[e*3+0], y = ev[e*3+1], z = ev[e*3+2];
        const float len = sqrtf(x*x + y*y + z*z);
        const float lc = fmaxf(len, 1e-8f);
        s_len[wave][lane] = lc;
        float Yl[16];
        sh_f32(x/lc, y/lc, z/lc, Yl);
#pragma unroll
        for (int i = 0; i < 16; ++i) s_Y[wave][lane*16+i] = Yl[i];
    }
    WAVE_SYNC();

    // cache this lane's node-feature row (el = lane>>4 fixed)
    const float* xrow = nf + (size_t)s_src[wave][lane >> 4]*FEAT;

    for (int g = 0; g < 4; ++g) {
        const int d3g = 2*g + 1;
        const int ntg = (4*d3g + 15) >> 4;   // 1,1,2,2 column tiles
        f32x4 Cw[2][2], Cb[2][2];
#pragma unroll
        for (int mt = 0; mt < 2; ++mt)
#pragma unroll
            for (int nt = 0; nt < 2; ++nt) {
                Cw[mt][nt] = (f32x4){0.f,0.f,0.f,0.f};
                Cb[mt][nt] = (f32x4){0.f,0.f,0.f,0.f};
            }

        for (int pi = L3START[g]; pi < L3START[g+1]; ++pi) {
            const int p  = L3PATHS[pi];
            const int l1 = P_L1[p], l2 = P_L2[p];
            const int d1 = 2*l1+1, d2 = 2*l2+1;
            const int zc = d1*d3g;

            // z[el][i][k] = sum_j Y[el][l2^2+j] * C[i][j][k]   (C via L1)
            const float* Cp0 = w3j + C_OFF[p];
            for (int idx = lane; idx < 4*zc; idx += 64) {
                const int el = idx / zc, r = idx - el*zc;
                const int i = r / d3g, k = r - i*d3g;
                const float* Cp = Cp0 + i*d2*d3g + k;
                const float* Yp = &s_Y[wave][el*16 + l2*l2];
                float acc = 0.f;
                for (int j = 0; j < d2; ++j) acc = fmaf(Yp[j], Cp[j*d3g], acc);
                s_zp[wave][el*49 + r] = acc;
            }
            WAVE_SYNC();

            // tmp + stage B-fragments (bf16 hi/lo) into wave-private LDS
            const int xoff = HIDDEN*l1*l1;
            switch (l1) {
                case 0: tmp_stage<1>(lane, d3g, xrow, s_zp[wave], s_Bhi[wave], s_Blo[wave], xoff); break;
                case 1: tmp_stage<3>(lane, d3g, xrow, s_zp[wave], s_Bhi[wave], s_Blo[wave], xoff); break;
                case 2: tmp_stage<5>(lane, d3g, xrow, s_zp[wave], s_Bhi[wave], s_Blo[wave], xoff); break;
                default: tmp_stage<7>(lane, d3g, xrow, s_zp[wave], s_Bhi[wave], s_Blo[wave], xoff); break;
            }
            WAVE_SYNC();

            // GEMM: D[w][c] += W^T[w][u] * tmp[u][c], K=32, 3-pass hi/lo split
            bf16x8 awh[2], awl[2], abh[2], abl[2];
#pragma unroll
            for (int mt = 0; mt < 2; ++mt) {
                const int m = mt*16 + ln;
                const int ao = p*1024 + m*32 + lq*8;
                awh[mt] = *(const bf16x8*)(Awhi + ao);
                awl[mt] = *(const bf16x8*)(Awlo + ao);
                abh[mt] = *(const bf16x8*)(Abhi + ao);
                abl[mt] = *(const bf16x8*)(Ablo + ao);
            }
#pragma unroll
            for (int nt = 0; nt < 2; ++nt) {
                if (nt < ntg) {
                    const int bo = (nt*16 + ln)*40 + lq*8;
                    const bf16x8 bh = *(const bf16x8*)(s_Bhi[wave] + bo);
                    const bf16x8 bl = *(const bf16x8*)(s_Blo[wave] + bo);
#pragma unroll
                    for (int mt = 0; mt < 2; ++mt) {
                        Cw[mt][nt] = __builtin_amdgcn_mfma_f32_16x16x32_bf16(awh[mt], bh, Cw[mt][nt], 0, 0, 0);
                        Cw[mt][nt] = __builtin_amdgcn_mfma_f32_16x16x32_bf16(awh[mt], bl, Cw[mt][nt], 0, 0, 0);
                        Cw[mt][nt] = __builtin_amdgcn_mfma_f32_16x16x32_bf16(awl[mt], bh, Cw[mt][nt], 0, 0, 0);
                        Cb[mt][nt] = __builtin_amdgcn_mfma_f32_16x16x32_bf16(abh[mt], bh, Cb[mt][nt], 0, 0, 0);
                        Cb[mt][nt] = __builtin_amdgcn_mfma_f32_16x16x32_bf16(abh[mt], bl, Cb[mt][nt], 0, 0, 0);
                        Cb[mt][nt] = __builtin_amdgcn_mfma_f32_16x16x32_bf16(abl[mt], bh, Cb[mt][nt], 0, 0, 0);
                    }
                }
            }
            WAVE_SYNC();  // B reads done before next path's tmp_stage overwrites
        }

        // group epilogue: msg = len*Cw + Cb  (wave-private, unique owners)
#pragma unroll
        for (int nt = 0; nt < 2; ++nt) {
            if (nt < ntg) {
                const int c = nt*16 + ln;
                if (c < 4*d3g) {
                    const int el = c/d3g;
                    const int k  = c - el*d3g;
                    const float len = s_len[wave][el];
                    float* mp = &s_msg[wave][el*FEAT + OFF3[g] + k];
#pragma unroll
                    for (int mt = 0; mt < 2; ++mt) {
#pragma unroll
                        for (int r = 0; r < 4; ++r) {
                            const int w = mt*16 + lq*4 + r;
                            mp[w*d3g] = fmaf(len, Cw[mt][nt][r], Cb[mt][nt][r]);
                        }
                    }
                }
            }
        }
    }
    WAVE_SYNC();

    // wave-local coalesced scatter: 4 edges x 512, 32 atomics/lane
    for (int i = lane; i < 4*FEAT; i += 64) {
        const int el = i >> 9, m = i & 511;
        atomicAdd(&out[(size_t)s_dst[wave][el]*FEAT + m], s_msg[wave][i]);
    }
}

extern "C" void kernel_launch(void* const* d_in, const int* in_sizes, int n_in,
                              void* d_out, int out_size, void* d_ws, size_t ws_size,
                              hipStream_t stream) {
    const float* nf   = (const float*)d_in[0];
    const int*   eidx = (const int*)  d_in[1];
    const float* ev   = (const float*)d_in[2];
    const float* ww   = (const float*)d_in[3];
    const float* wb   = (const float*)d_in[4];
    float* out = (float*)d_out;

    float* w3j = (float*)d_ws;                                   // 7500 B
    unsigned short* Awhi = (unsigned short*)((char*)d_ws + 16384);
    unsigned short* Awlo = Awhi + N_PATHS*1024;
    unsigned short* Abhi = Awlo + N_PATHS*1024;
    unsigned short* Ablo = Abhi + N_PATHS*1024;                  // ends at 204800 B

    hipMemsetAsync(d_out, 0, (size_t)out_size * sizeof(float), stream);
    w3j_setup_kernel<<<N_PATHS, 512, 0, stream>>>(ww, wb, w3j, Awhi, Awlo, Abhi, Ablo);
    edge_kernel<<<N_EDGES/EB, BLK, 0, stream>>>(nf, eidx, ev, w3j, Awhi, Awlo, Abhi, Ablo, out);
}